// Round 1
// baseline (95.797 us; speedup 1.0000x reference)
//
#include <hip/hip_runtime.h>
#include <cstdint>
#include <cstddef>

#define NB 2
#define NPT 20000
#define KNN 17
#define CH 128
#define NT16 (NPT/16)
#define EPSV 1e-5f

typedef short short8 __attribute__((ext_vector_type(8)));
typedef float f32x4 __attribute__((ext_vector_type(4)));

__device__ __forceinline__ unsigned short f2bf(float x) {
    union { float f; unsigned int u; } v; v.f = x;
    unsigned int r = v.u + 0x7FFFu + ((v.u >> 16) & 1u);   // RNE
    return (unsigned short)(r >> 16);
}
__device__ __forceinline__ float bf2f(unsigned short s) {
    union { unsigned int u; float f; } v; v.u = ((unsigned int)s) << 16;
    return v.f;
}

// Kernel 1: F[b][n][g] = relu(bn(Wf @ feats[:, n]))  stored bf16, point-major.
__global__ __launch_bounds__(256) void k_feats(
    const float* __restrict__ feats, const float* __restrict__ Wf,
    const float* __restrict__ bfv, const float* __restrict__ gf,
    const float* __restrict__ betaf, const float* __restrict__ mf,
    const float* __restrict__ vf, unsigned short* __restrict__ Fout)
{
    __shared__ unsigned short A_lds[16][136];   // 16 pts x 128 c, +8 pad
    const int t   = threadIdx.x;
    const int b   = blockIdx.x / NT16;
    const int n0  = (blockIdx.x % NT16) * 16;

    // stage feats^T tile (16 points x 128 ch) -> bf16 LDS
    {
        const int p = t & 15, j = t >> 4;          // lanes: p fast -> coalesced
        const float* src = feats + (size_t)b*CH*NPT + n0 + p;
        #pragma unroll
        for (int jj = 0; jj < 8; ++jj) {
            int c = j*8 + jj;
            A_lds[p][c] = f2bf(src[(size_t)c*NPT]);
        }
    }

    const int lane = t & 63, wid = t >> 6;
    const int h = lane >> 4, r16 = lane & 15;
    const int gb = wid * 32;

    // B fragments (Wf rows) + folded BN coeffs
    short8 bfrag[2][4];
    float sf[2], tf[2];
    #pragma unroll
    for (int T = 0; T < 2; ++T) {
        int g = gb + T*16 + r16;
        #pragma unroll
        for (int s = 0; s < 4; ++s) {
            const float* wrow = Wf + g*CH + s*32 + h*8;
            float4 w0 = *(const float4*)(wrow);
            float4 w1 = *(const float4*)(wrow + 4);
            short8 f;
            f[0]=(short)f2bf(w0.x); f[1]=(short)f2bf(w0.y);
            f[2]=(short)f2bf(w0.z); f[3]=(short)f2bf(w0.w);
            f[4]=(short)f2bf(w1.x); f[5]=(short)f2bf(w1.y);
            f[6]=(short)f2bf(w1.z); f[7]=(short)f2bf(w1.w);
            bfrag[T][s] = f;
        }
        float inv = gf[g] * rsqrtf(vf[g] + EPSV);
        sf[T] = inv;
        tf[T] = bfv[g]*inv + betaf[g] - mf[g]*inv;
    }
    __syncthreads();

    #pragma unroll
    for (int T = 0; T < 2; ++T) {
        f32x4 acc = {0.f, 0.f, 0.f, 0.f};
        #pragma unroll
        for (int s = 0; s < 4; ++s) {
            short8 a = *(const short8*)&A_lds[r16][s*32 + h*8];
            acc = __builtin_amdgcn_mfma_f32_16x16x32_bf16(a, bfrag[T][s], acc, 0, 0, 0);
        }
        int g = gb + T*16 + r16;
        #pragma unroll
        for (int r = 0; r < 4; ++r) {
            float y = fmaxf(sf[T]*acc[r] + tf[T], 0.f);
            int n = n0 + 4*h + r;                       // D: row = 4*(lane>>4)+reg
            Fout[((size_t)b*NPT + n)*CH + g] = f2bf(y);
        }
    }
}

// Kernel 2: per 16-point tile, loop over k: A-rows = relu(bn(Wd·δ)) * F[idx],
// MFMA with Wp, BN+ReLU in fp32, accumulate over k, write out[b][g][n].
__global__ __launch_bounds__(256) void k_main(
    const float* __restrict__ pts, const int* __restrict__ knn,
    const unsigned short* __restrict__ F,
    const float* __restrict__ Wd, const float* __restrict__ bd,
    const float* __restrict__ gd, const float* __restrict__ betad,
    const float* __restrict__ md, const float* __restrict__ vd,
    const float* __restrict__ Wp, const float* __restrict__ bp,
    const float* __restrict__ gp, const float* __restrict__ betap,
    const float* __restrict__ mp, const float* __restrict__ vp,
    float* __restrict__ out)
{
    __shared__ unsigned short A_lds[16][136];
    __shared__ int   idx_lds[16*KNN];
    __shared__ float delta_lds[3][16*KNN];
    __shared__ float4 dcoef[CH];

    const int t  = threadIdx.x;
    const int b  = blockIdx.x / NT16;
    const int n0 = (blockIdx.x % NT16) * 16;

    for (int e = t; e < 16*KNN; e += 256)
        idx_lds[e] = knn[((size_t)b*NPT + n0)*KNN + e];
    if (t < CH) {
        float inv = gd[t] * rsqrtf(vd[t] + EPSV);
        float td  = bd[t]*inv + betad[t] - md[t]*inv;
        dcoef[t]  = make_float4(Wd[t*3]*inv, Wd[t*3+1]*inv, Wd[t*3+2]*inv, td);
    }
    __syncthreads();

    // gather neighbor deltas into LDS
    for (int e = t; e < 3*16*KNN; e += 256) {
        int coord = e / (16*KNN), jj = e - coord*(16*KNN);
        int p = jj / KNN;
        const float* pc = pts + ((size_t)b*3 + coord)*NPT;
        delta_lds[coord][jj] = pc[idx_lds[jj]] - pc[n0 + p];
    }

    const int p_t = t >> 4, j_t = t & 15, c0 = j_t*8;   // staging row/col-block
    const int lane = t & 63, wid = t >> 6;
    const int h = lane >> 4, r16 = lane & 15;
    const int gb = wid * 32;

    // B fragments from Wp + folded BN coeffs
    short8 bfrag[2][4];
    float sp[2], tp[2];
    #pragma unroll
    for (int T = 0; T < 2; ++T) {
        int g = gb + T*16 + r16;
        #pragma unroll
        for (int s = 0; s < 4; ++s) {
            const float* wrow = Wp + g*CH + s*32 + h*8;
            float4 w0 = *(const float4*)(wrow);
            float4 w1 = *(const float4*)(wrow + 4);
            short8 f;
            f[0]=(short)f2bf(w0.x); f[1]=(short)f2bf(w0.y);
            f[2]=(short)f2bf(w0.z); f[3]=(short)f2bf(w0.w);
            f[4]=(short)f2bf(w1.x); f[5]=(short)f2bf(w1.y);
            f[6]=(short)f2bf(w1.z); f[7]=(short)f2bf(w1.w);
            bfrag[T][s] = f;
        }
        float inv = gp[g] * rsqrtf(vp[g] + EPSV);
        sp[T] = inv;
        tp[T] = bp[g]*inv + betap[g] - mp[g]*inv;
    }
    __syncthreads();   // delta_lds + dcoef ready

    float4 dcf[8];
    #pragma unroll
    for (int q = 0; q < 8; ++q) dcf[q] = dcoef[c0 + q];

    f32x4 facc[2] = {{0.f,0.f,0.f,0.f},{0.f,0.f,0.f,0.f}};

    for (int k = 0; k < KNN; ++k) {
        // ---- stage A rows: v[c] = relu(bn(Wd·δ))[c] * F[idx][c], bf16 ----
        {
            int jj = p_t*KNN + k;
            float dx = delta_lds[0][jj], dy = delta_lds[1][jj], dz = delta_lds[2][jj];
            int nb = idx_lds[jj];
            const uint4 fr = *(const uint4*)(F + ((size_t)b*NPT + nb)*CH + c0);
            unsigned int fw[4] = {fr.x, fr.y, fr.z, fr.w};
            unsigned short vo[8];
            #pragma unroll
            for (int q = 0; q < 8; ++q) {
                float4 dc = dcf[q];
                float d = fmaf(dc.x, dx, fmaf(dc.y, dy, fmaf(dc.z, dz, dc.w)));
                d = fmaxf(d, 0.f);
                unsigned short fu = (unsigned short)(fw[q>>1] >> ((q&1)*16));
                vo[q] = f2bf(d * bf2f(fu));
            }
            uint4 pack;
            pack.x = (unsigned)vo[0] | ((unsigned)vo[1] << 16);
            pack.y = (unsigned)vo[2] | ((unsigned)vo[3] << 16);
            pack.z = (unsigned)vo[4] | ((unsigned)vo[5] << 16);
            pack.w = (unsigned)vo[6] | ((unsigned)vo[7] << 16);
            *(uint4*)&A_lds[p_t][c0] = pack;
        }
        __syncthreads();

        // ---- MFMA: y = Wp @ v for 16 rows, then BN+ReLU+accumulate ----
        #pragma unroll
        for (int T = 0; T < 2; ++T) {
            f32x4 acc = {0.f, 0.f, 0.f, 0.f};
            #pragma unroll
            for (int s = 0; s < 4; ++s) {
                short8 a = *(const short8*)&A_lds[r16][s*32 + h*8];
                acc = __builtin_amdgcn_mfma_f32_16x16x32_bf16(a, bfrag[T][s], acc, 0, 0, 0);
            }
            #pragma unroll
            for (int r = 0; r < 4; ++r)
                facc[T][r] += fmaxf(sp[T]*acc[r] + tp[T], 0.f);
        }
        __syncthreads();
    }

    #pragma unroll
    for (int T = 0; T < 2; ++T) {
        int g = gb + T*16 + r16;
        *(f32x4*)(out + ((size_t)b*CH + g)*NPT + n0 + 4*h) = facc[T];
    }
}

extern "C" void kernel_launch(void* const* d_in, const int* in_sizes, int n_in,
                              void* d_out, int out_size, void* d_ws, size_t ws_size,
                              hipStream_t stream)
{
    const float* feats = (const float*)d_in[0];
    const float* pts   = (const float*)d_in[1];
    const int*   knn   = (const int*)d_in[2];
    const float* Wd    = (const float*)d_in[3];
    const float* bd    = (const float*)d_in[4];
    const float* gd    = (const float*)d_in[5];
    const float* betad = (const float*)d_in[6];
    const float* md    = (const float*)d_in[7];
    const float* vd    = (const float*)d_in[8];
    const float* Wf    = (const float*)d_in[9];
    const float* bfv   = (const float*)d_in[10];
    const float* gf    = (const float*)d_in[11];
    const float* betaf = (const float*)d_in[12];
    const float* mf    = (const float*)d_in[13];
    const float* vf    = (const float*)d_in[14];
    const float* Wp    = (const float*)d_in[15];
    const float* bp    = (const float*)d_in[16];
    const float* gp    = (const float*)d_in[17];
    const float* betap = (const float*)d_in[18];
    const float* mp    = (const float*)d_in[19];
    const float* vp    = (const float*)d_in[20];
    float* out = (float*)d_out;
    unsigned short* Fws = (unsigned short*)d_ws;   // B*N*128 bf16 = 10.24 MB

    dim3 grid(NB * NT16);
    k_feats<<<grid, 256, 0, stream>>>(feats, Wf, bfv, gf, betaf, mf, vf, Fws);
    k_main <<<grid, 256, 0, stream>>>(pts, knn, Fws, Wd, bd, gd, betad, md, vd,
                                      Wp, bp, gp, betap, mp, vp, out);
}

// Round 2
// 78.369 us; speedup vs baseline: 1.2224x; 1.2224x over previous
//
#include <hip/hip_runtime.h>
#include <hip/hip_bf16.h>
#include <cstdint>
#include <cstddef>

#define NB 2
#define NPT 20000
#define KNN 17
#define CH 128
#define NT16 (NPT/16)
#define NT32 (NPT/32)
#define EPSV 1e-5f

typedef short short8 __attribute__((ext_vector_type(8)));
typedef float f32x4 __attribute__((ext_vector_type(4)));

__device__ __forceinline__ unsigned short f2bf(float x) {
    union { float f; unsigned int u; } v; v.f = x;
    unsigned int r = v.u + 0x7FFFu + ((v.u >> 16) & 1u);   // RNE
    return (unsigned short)(r >> 16);
}
__device__ __forceinline__ float bf_lo(unsigned w) {
    union { unsigned u; float f; } v; v.u = w << 16; return v.f;
}
__device__ __forceinline__ float bf_hi(unsigned w) {
    union { unsigned u; float f; } v; v.u = w & 0xffff0000u; return v.f;
}
__device__ __forceinline__ unsigned pack_bf2(float a, float b) {
    __hip_bfloat162 h2 = __float22bfloat162_rn(make_float2(a, b));
    union { __hip_bfloat162 h; unsigned u; } cv; cv.h = h2; return cv.u;
}

// ---------------- Kernel 1: F[b][n][g] = relu(bn(Wf @ feats[:,n])), bf16 ----
__global__ __launch_bounds__(256) void k_feats(
    const float* __restrict__ feats, const float* __restrict__ Wf,
    const float* __restrict__ bfv, const float* __restrict__ gf,
    const float* __restrict__ betaf, const float* __restrict__ mf,
    const float* __restrict__ vf, unsigned short* __restrict__ Fout)
{
    __shared__ unsigned short A_lds[32][136];   // [pt][ch]
    __shared__ unsigned short O_lds[32][136];   // [pt][g]
    const int t  = threadIdx.x;
    const int b  = blockIdx.x / NT32;
    const int n0 = (blockIdx.x % NT32) * 32;

    // stage feats tile: 128 ch x 32 pts, coalesced float4 reads, transpose to [pt][ch]
    {
        const int chunk = t & 7;        // 4-point group
        const int cbase = t >> 3;       // 32 channels per pass
        const float* base = feats + (size_t)b*CH*NPT + n0 + chunk*4;
        #pragma unroll
        for (int it = 0; it < 4; ++it) {
            int c = it*32 + cbase;
            float4 v = *(const float4*)(base + (size_t)c*NPT);
            A_lds[chunk*4+0][c] = f2bf(v.x);
            A_lds[chunk*4+1][c] = f2bf(v.y);
            A_lds[chunk*4+2][c] = f2bf(v.z);
            A_lds[chunk*4+3][c] = f2bf(v.w);
        }
    }

    const int lane = t & 63, wid = t >> 6;
    const int h = lane >> 4, r16 = lane & 15;
    const int gb = wid * 32;

    short8 bfrag[2][4];
    float sf[2], tf[2];
    #pragma unroll
    for (int T = 0; T < 2; ++T) {
        int g = gb + T*16 + r16;
        #pragma unroll
        for (int s = 0; s < 4; ++s) {
            const float* wrow = Wf + g*CH + s*32 + h*8;
            float4 w0 = *(const float4*)(wrow);
            float4 w1 = *(const float4*)(wrow + 4);
            short8 f;
            f[0]=(short)f2bf(w0.x); f[1]=(short)f2bf(w0.y);
            f[2]=(short)f2bf(w0.z); f[3]=(short)f2bf(w0.w);
            f[4]=(short)f2bf(w1.x); f[5]=(short)f2bf(w1.y);
            f[6]=(short)f2bf(w1.z); f[7]=(short)f2bf(w1.w);
            bfrag[T][s] = f;
        }
        float inv = gf[g] * rsqrtf(vf[g] + EPSV);
        sf[T] = inv;
        tf[T] = bfv[g]*inv + betaf[g] - mf[g]*inv;
    }
    __syncthreads();

    #pragma unroll
    for (int sub = 0; sub < 2; ++sub) {
        #pragma unroll
        for (int T = 0; T < 2; ++T) {
            f32x4 acc = {0.f, 0.f, 0.f, 0.f};
            #pragma unroll
            for (int s = 0; s < 4; ++s) {
                short8 a = *(const short8*)&A_lds[sub*16 + r16][s*32 + h*8];
                acc = __builtin_amdgcn_mfma_f32_16x16x32_bf16(a, bfrag[T][s], acc, 0, 0, 0);
            }
            #pragma unroll
            for (int r = 0; r < 4; ++r) {
                float y = fmaxf(fmaf(sf[T], acc[r], tf[T]), 0.f);
                O_lds[sub*16 + 4*h + r][gb + T*16 + r16] = f2bf(y);
            }
        }
    }
    __syncthreads();

    // coalesced copy out: 32 pts x 256B
    {
        const int pp = t >> 3, cc = (t & 7) * 16;
        uint4 v0 = *(const uint4*)&O_lds[pp][cc];
        uint4 v1 = *(const uint4*)&O_lds[pp][cc + 8];
        unsigned short* dst = Fout + ((size_t)b*NPT + n0 + pp)*CH + cc;
        *(uint4*)dst = v0;
        *(uint4*)(dst + 8) = v1;
    }
}

// ---------------- Kernel 2: main fused gather + product + Wp GEMM ----------
struct Pref { float dx, dy, dz; uint4 fr; };

__device__ __forceinline__ Pref issueK(const int* __restrict__ idx_lds, int p_t, int k,
    const float* __restrict__ px, const float* __restrict__ py,
    const float* __restrict__ pz, const unsigned short* __restrict__ Fb, int c0)
{
    Pref P;
    int nb = idx_lds[p_t*KNN + k];
    P.dx = px[nb]; P.dy = py[nb]; P.dz = pz[nb];
    P.fr = *(const uint4*)(Fb + (size_t)nb*CH + c0);
    return P;
}

__device__ __forceinline__ void stageRow(unsigned short (*A)[136], int p_t, int c0,
    const float4* dcf, const float* tq, const Pref& P)
{
    unsigned fw0 = P.fr.x, fw1 = P.fr.y, fw2 = P.fr.z, fw3 = P.fr.w;
    float pr[8];
    const unsigned fws[4] = {fw0, fw1, fw2, fw3};
    #pragma unroll
    for (int q = 0; q < 8; ++q) {
        float d = fmaf(dcf[q].x, P.dx, fmaf(dcf[q].y, P.dy, fmaf(dcf[q].z, P.dz, tq[q])));
        d = fmaxf(d, 0.f);
        float f = (q & 1) ? bf_hi(fws[q >> 1]) : bf_lo(fws[q >> 1]);
        pr[q] = d * f;
    }
    uint4 pack;
    pack.x = pack_bf2(pr[0], pr[1]);
    pack.y = pack_bf2(pr[2], pr[3]);
    pack.z = pack_bf2(pr[4], pr[5]);
    pack.w = pack_bf2(pr[6], pr[7]);
    *(uint4*)&A[p_t][c0] = pack;
}

__device__ __forceinline__ void mfmaPlane(const unsigned short (*A)[136], int r16, int h,
    const short8 bfrag[2][4], const float* sp, const float* tp, f32x4* facc)
{
    #pragma unroll
    for (int T = 0; T < 2; ++T) {
        f32x4 acc = {0.f, 0.f, 0.f, 0.f};
        #pragma unroll
        for (int s = 0; s < 4; ++s) {
            short8 a = *(const short8*)&A[r16][s*32 + h*8];
            acc = __builtin_amdgcn_mfma_f32_16x16x32_bf16(a, bfrag[T][s], acc, 0, 0, 0);
        }
        #pragma unroll
        for (int r = 0; r < 4; ++r)
            facc[T][r] += fmaxf(fmaf(sp[T], acc[r], tp[T]), 0.f);
    }
}

__global__ __launch_bounds__(256) void k_main(
    const float* __restrict__ pts, const int* __restrict__ knn,
    const unsigned short* __restrict__ F,
    const float* __restrict__ Wd, const float* __restrict__ bd,
    const float* __restrict__ gd, const float* __restrict__ betad,
    const float* __restrict__ md, const float* __restrict__ vd,
    const float* __restrict__ Wp, const float* __restrict__ bp,
    const float* __restrict__ gp, const float* __restrict__ betap,
    const float* __restrict__ mp, const float* __restrict__ vp,
    float* __restrict__ out)
{
    __shared__ unsigned short A2[2][16][136];   // double-buffered A plane
    __shared__ int   idx_lds[16*KNN];
    __shared__ float4 dcoef[CH];

    const int t  = threadIdx.x;
    const int b  = blockIdx.x / NT16;
    const int n0 = (blockIdx.x % NT16) * 16;

    for (int e = t; e < 16*KNN; e += 256)
        idx_lds[e] = knn[((size_t)b*NPT + n0)*KNN + e];
    if (t < CH) {
        float inv = gd[t] * rsqrtf(vd[t] + EPSV);
        float td  = bd[t]*inv + betad[t] - md[t]*inv;
        dcoef[t]  = make_float4(Wd[t*3]*inv, Wd[t*3+1]*inv, Wd[t*3+2]*inv, td);
    }
    __syncthreads();

    const int p_t = t >> 4, c0 = (t & 15) * 8;     // staging assignment
    const int lane = t & 63, wid = t >> 6;
    const int h = lane >> 4, r16 = lane & 15;
    const int gb = wid * 32;

    const float* px = pts + (size_t)b*3*NPT;
    const float* py = px + NPT;
    const float* pz = py + NPT;
    const unsigned short* Fb = F + (size_t)b*NPT*CH;

    // prefetch planes 0,1 early (latency hiding under setup below)
    Pref PA = issueK(idx_lds, p_t, 0, px, py, pz, Fb, c0);
    Pref PB = issueK(idx_lds, p_t, 1, px, py, pz, Fb, c0);

    // B fragments from Wp + folded BN coeffs
    short8 bfrag[2][4];
    float sp[2], tp[2];
    #pragma unroll
    for (int T = 0; T < 2; ++T) {
        int g = gb + T*16 + r16;
        #pragma unroll
        for (int s = 0; s < 4; ++s) {
            const float* wrow = Wp + g*CH + s*32 + h*8;
            float4 w0 = *(const float4*)(wrow);
            float4 w1 = *(const float4*)(wrow + 4);
            short8 f;
            f[0]=(short)f2bf(w0.x); f[1]=(short)f2bf(w0.y);
            f[2]=(short)f2bf(w0.z); f[3]=(short)f2bf(w0.w);
            f[4]=(short)f2bf(w1.x); f[5]=(short)f2bf(w1.y);
            f[6]=(short)f2bf(w1.z); f[7]=(short)f2bf(w1.w);
            bfrag[T][s] = f;
        }
        float inv = gp[g] * rsqrtf(vp[g] + EPSV);
        sp[T] = inv;
        tp[T] = bp[g]*inv + betap[g] - mp[g]*inv;
    }

    // per-thread d-branch coefficients; fold center into the bias term
    float4 dcf[8];
    float  tq[8];
    {
        float cx = px[n0 + p_t], cy = py[n0 + p_t], cz = pz[n0 + p_t];
        #pragma unroll
        for (int q = 0; q < 8; ++q) {
            dcf[q] = dcoef[c0 + q];
            tq[q]  = dcf[q].w - (dcf[q].x*cx + dcf[q].y*cy + dcf[q].z*cz);
        }
    }

    f32x4 facc[2] = {{0.f,0.f,0.f,0.f},{0.f,0.f,0.f,0.f}};

    // prologue: stage plane 0, issue plane 2
    stageRow(A2[0], p_t, c0, dcf, tq, PA);
    PA = issueK(idx_lds, p_t, 2, px, py, pz, Fb, c0);
    __syncthreads();

    #pragma unroll 1
    for (int k = 0; k < 16; k += 2) {
        // half A: MFMA plane k (buf0); stage plane k+1 -> buf1; issue k+3
        mfmaPlane(A2[0], r16, h, bfrag, sp, tp, facc);
        stageRow(A2[1], p_t, c0, dcf, tq, PB);
        if (k + 3 < KNN) PB = issueK(idx_lds, p_t, k+3, px, py, pz, Fb, c0);
        __syncthreads();
        // half B: MFMA plane k+1 (buf1); stage plane k+2 -> buf0; issue k+4
        mfmaPlane(A2[1], r16, h, bfrag, sp, tp, facc);
        stageRow(A2[0], p_t, c0, dcf, tq, PA);
        if (k + 4 < KNN) PA = issueK(idx_lds, p_t, k+4, px, py, pz, Fb, c0);
        __syncthreads();
    }
    mfmaPlane(A2[0], r16, h, bfrag, sp, tp, facc);   // plane 16

    #pragma unroll
    for (int T = 0; T < 2; ++T) {
        int g = gb + T*16 + r16;
        *(f32x4*)(out + ((size_t)b*CH + g)*NPT + n0 + 4*h) = facc[T];
    }
}

extern "C" void kernel_launch(void* const* d_in, const int* in_sizes, int n_in,
                              void* d_out, int out_size, void* d_ws, size_t ws_size,
                              hipStream_t stream)
{
    const float* feats = (const float*)d_in[0];
    const float* pts   = (const float*)d_in[1];
    const int*   knn   = (const int*)d_in[2];
    const float* Wd    = (const float*)d_in[3];
    const float* bd    = (const float*)d_in[4];
    const float* gd    = (const float*)d_in[5];
    const float* betad = (const float*)d_in[6];
    const float* md    = (const float*)d_in[7];
    const float* vd    = (const float*)d_in[8];
    const float* Wf    = (const float*)d_in[9];
    const float* bfv   = (const float*)d_in[10];
    const float* gf    = (const float*)d_in[11];
    const float* betaf = (const float*)d_in[12];
    const float* mf    = (const float*)d_in[13];
    const float* vf    = (const float*)d_in[14];
    const float* Wp    = (const float*)d_in[15];
    const float* bp    = (const float*)d_in[16];
    const float* gp    = (const float*)d_in[17];
    const float* betap = (const float*)d_in[18];
    const float* mp    = (const float*)d_in[19];
    const float* vp    = (const float*)d_in[20];
    float* out = (float*)d_out;
    unsigned short* Fws = (unsigned short*)d_ws;   // B*N*128 bf16 = 10.24 MB

    k_feats<<<dim3(NB * NT32), 256, 0, stream>>>(feats, Wf, bfv, gf, betaf, mf, vf, Fws);
    k_main <<<dim3(NB * NT16), 256, 0, stream>>>(pts, knn, Fws, Wd, bd, gd, betad, md, vd,
                                                 Wp, bp, gp, betap, mp, vp, out);
}

// Round 3
// 74.627 us; speedup vs baseline: 1.2837x; 1.0501x over previous
//
#include <hip/hip_runtime.h>
#include <hip/hip_bf16.h>
#include <cstdint>
#include <cstddef>

#define NB 2
#define NPT 20000
#define KNN 17
#define CH 128
#define NT16 (NPT/16)
#define NT32 (NPT/32)
#define EPSV 1e-5f

typedef short short8 __attribute__((ext_vector_type(8)));
typedef float f32x4 __attribute__((ext_vector_type(4)));
typedef float f32x2 __attribute__((ext_vector_type(2)));

__device__ __forceinline__ unsigned short f2bf(float x) {
    union { float f; unsigned int u; } v; v.f = x;
    unsigned int r = v.u + 0x7FFFu + ((v.u >> 16) & 1u);   // RNE
    return (unsigned short)(r >> 16);
}
__device__ __forceinline__ unsigned pack_bf2(float a, float b) {
    __hip_bfloat162 h2 = __float22bfloat162_rn(make_float2(a, b));
    union { __hip_bfloat162 h; unsigned u; } cv; cv.h = h2; return cv.u;
}
__device__ __forceinline__ f32x2 bfpair(unsigned w) {
    union { unsigned u; float f; } lo, hi;
    lo.u = w << 16; hi.u = w & 0xffff0000u;
    f32x2 r; r[0] = lo.f; r[1] = hi.f; return r;
}
// convert 8 consecutive f32 weights -> short8 bf16 fragment via cvt_pk pairs
__device__ __forceinline__ short8 packrow(const float* wrow) {
    float4 w0 = *(const float4*)(wrow);
    float4 w1 = *(const float4*)(wrow + 4);
    uint4 uu;
    uu.x = pack_bf2(w0.x, w0.y); uu.y = pack_bf2(w0.z, w0.w);
    uu.z = pack_bf2(w1.x, w1.y); uu.w = pack_bf2(w1.z, w1.w);
    union { uint4 u; short8 s; } cv; cv.u = uu; return cv.s;
}

// ---------------- Kernel 1: F[b][n][g] = relu(bn(Wf @ feats[:,n])), bf16 ----
__global__ __launch_bounds__(256) void k_feats(
    const float* __restrict__ feats, const float* __restrict__ Wf,
    const float* __restrict__ bfv, const float* __restrict__ gf,
    const float* __restrict__ betaf, const float* __restrict__ mf,
    const float* __restrict__ vf, unsigned short* __restrict__ Fout)
{
    __shared__ unsigned short A_lds[32][136];   // [pt][ch]
    __shared__ unsigned short O_lds[32][136];   // [pt][g]
    const int t  = threadIdx.x;
    const int b  = blockIdx.x / NT32;
    const int n0 = (blockIdx.x % NT32) * 32;

    // stage feats tile: 128 ch x 32 pts, coalesced float4 reads, transpose to [pt][ch]
    {
        const int chunk = t & 7;        // 4-point group
        const int cbase = t >> 3;       // 32 channels per pass
        const float* base = feats + (size_t)b*CH*NPT + n0 + chunk*4;
        #pragma unroll
        for (int it = 0; it < 4; ++it) {
            int c = it*32 + cbase;
            float4 v = *(const float4*)(base + (size_t)c*NPT);
            A_lds[chunk*4+0][c] = f2bf(v.x);
            A_lds[chunk*4+1][c] = f2bf(v.y);
            A_lds[chunk*4+2][c] = f2bf(v.z);
            A_lds[chunk*4+3][c] = f2bf(v.w);
        }
    }

    const int lane = t & 63, wid = t >> 6;
    const int h = lane >> 4, r16 = lane & 15;
    const int gb = wid * 32;

    short8 bfrag[2][4];
    float sf[2], tf[2];
    #pragma unroll
    for (int T = 0; T < 2; ++T) {
        int g = gb + T*16 + r16;
        #pragma unroll
        for (int s = 0; s < 4; ++s)
            bfrag[T][s] = packrow(Wf + g*CH + s*32 + h*8);
        float inv = gf[g] * rsqrtf(vf[g] + EPSV);
        sf[T] = inv;
        tf[T] = bfv[g]*inv + betaf[g] - mf[g]*inv;
    }
    __syncthreads();

    #pragma unroll
    for (int sub = 0; sub < 2; ++sub) {
        short8 a[4];
        #pragma unroll
        for (int s = 0; s < 4; ++s)
            a[s] = *(const short8*)&A_lds[sub*16 + r16][s*32 + h*8];
        #pragma unroll
        for (int T = 0; T < 2; ++T) {
            f32x4 acc = {0.f, 0.f, 0.f, 0.f};
            #pragma unroll
            for (int s = 0; s < 4; ++s)
                acc = __builtin_amdgcn_mfma_f32_16x16x32_bf16(a[s], bfrag[T][s], acc, 0, 0, 0);
            #pragma unroll
            for (int r = 0; r < 4; ++r) {
                float y = fmaxf(fmaf(sf[T], acc[r], tf[T]), 0.f);
                O_lds[sub*16 + 4*h + r][gb + T*16 + r16] = f2bf(y);
            }
        }
    }
    __syncthreads();

    // coalesced copy out: 32 pts x 256B
    {
        const int pp = t >> 3, cc = (t & 7) * 16;
        uint4 v0 = *(const uint4*)&O_lds[pp][cc];
        uint4 v1 = *(const uint4*)&O_lds[pp][cc + 8];
        unsigned short* dst = Fout + ((size_t)b*NPT + n0 + pp)*CH + cc;
        *(uint4*)dst = v0;
        *(uint4*)(dst + 8) = v1;
    }
}

// ---------------- Kernel 2: main fused gather + product + Wp GEMM ----------
struct Pref { float dx, dy, dz; uint4 fr; };

__device__ __forceinline__ Pref issueK(const int* __restrict__ idx_row, int k,
    const float* __restrict__ px, const float* __restrict__ py,
    const float* __restrict__ pz, const unsigned short* __restrict__ Fb, int c0)
{
    Pref P;
    int nb = idx_row[k];
    P.dx = px[nb]; P.dy = py[nb]; P.dz = pz[nb];
    P.fr = *(const uint4*)(Fb + (size_t)nb*CH + c0);
    return P;
}

__device__ __forceinline__ void stageRow(unsigned short (*A)[136], int p_t, int c0,
    const f32x2* wx2, const f32x2* wy2, const f32x2* wz2, const f32x2* tq2,
    const Pref& P)
{
    const unsigned fw[4] = {P.fr.x, P.fr.y, P.fr.z, P.fr.w};
    const f32x2 zero2 = {0.f, 0.f};
    unsigned pk[4];
    #pragma unroll
    for (int q = 0; q < 4; ++q) {
        f32x2 d = wx2[q]*P.dx + wy2[q]*P.dy + wz2[q]*P.dz + tq2[q];
        d = __builtin_elementwise_max(d, zero2);
        f32x2 pr = d * bfpair(fw[q]);
        pk[q] = pack_bf2(pr[0], pr[1]);
    }
    uint4 pack; pack.x = pk[0]; pack.y = pk[1]; pack.z = pk[2]; pack.w = pk[3];
    *(uint4*)&A[p_t][c0] = pack;
}

__device__ __forceinline__ void mfmaPlane(const unsigned short (*A)[136], int r16, int h,
    const short8 bfrag[2][4], const float* spv, const float* tpv, f32x2 facc2[2][2])
{
    short8 a[4];
    #pragma unroll
    for (int s = 0; s < 4; ++s)
        a[s] = *(const short8*)&A[r16][s*32 + h*8];
    const f32x2 zero2 = {0.f, 0.f};
    #pragma unroll
    for (int T = 0; T < 2; ++T) {
        f32x4 acc = {0.f, 0.f, 0.f, 0.f};
        #pragma unroll
        for (int s = 0; s < 4; ++s)
            acc = __builtin_amdgcn_mfma_f32_16x16x32_bf16(a[s], bfrag[T][s], acc, 0, 0, 0);
        #pragma unroll
        for (int half = 0; half < 2; ++half) {
            f32x2 a2; a2[0] = acc[2*half]; a2[1] = acc[2*half+1];
            f32x2 y = a2 * spv[T] + tpv[T];
            y = __builtin_elementwise_max(y, zero2);
            facc2[T][half] += y;
        }
    }
}

__global__ __launch_bounds__(256) void k_main(
    const float* __restrict__ pts, const int* __restrict__ knn,
    const unsigned short* __restrict__ F,
    const float* __restrict__ Wd, const float* __restrict__ bd,
    const float* __restrict__ gd, const float* __restrict__ betad,
    const float* __restrict__ md, const float* __restrict__ vd,
    const float* __restrict__ Wp, const float* __restrict__ bp,
    const float* __restrict__ gp, const float* __restrict__ betap,
    const float* __restrict__ mp, const float* __restrict__ vp,
    float* __restrict__ out)
{
    __shared__ unsigned short A3[2][2][16][136];   // dbuf x 2 planes
    __shared__ int   idx_lds[16*KNN];
    __shared__ float4 dcoef[CH];

    const int t  = threadIdx.x;
    const int b  = blockIdx.x / NT16;
    const int n0 = (blockIdx.x % NT16) * 16;

    for (int e = t; e < 16*KNN; e += 256)
        idx_lds[e] = knn[((size_t)b*NPT + n0)*KNN + e];
    if (t < CH) {
        float inv = gd[t] * rsqrtf(vd[t] + EPSV);
        float td  = bd[t]*inv + betad[t] - md[t]*inv;
        dcoef[t]  = make_float4(Wd[t*3]*inv, Wd[t*3+1]*inv, Wd[t*3+2]*inv, td);
    }
    __syncthreads();

    const int p_t = t >> 4, c0 = (t & 15) * 8;     // staging assignment
    const int lane = t & 63, wid = t >> 6;
    const int h = lane >> 4, r16 = lane & 15;
    const int gb = wid * 32;

    const float* px = pts + (size_t)b*3*NPT;
    const float* py = px + NPT;
    const float* pz = py + NPT;
    const unsigned short* Fb = F + (size_t)b*NPT*CH;
    const int* idx_row = idx_lds + p_t*KNN;

    // prefetch planes 0,1 (hides under prologue setup)
    Pref PA = issueK(idx_row, 0, px, py, pz, Fb, c0);
    Pref PB = issueK(idx_row, 1, px, py, pz, Fb, c0);

    // B fragments from Wp (cvt_pk pairs) + folded BN coeffs
    short8 bfrag[2][4];
    float spv[2], tpv[2];
    #pragma unroll
    for (int T = 0; T < 2; ++T) {
        int g = gb + T*16 + r16;
        #pragma unroll
        for (int s = 0; s < 4; ++s)
            bfrag[T][s] = packrow(Wp + g*CH + s*32 + h*8);
        float inv = gp[g] * rsqrtf(vp[g] + EPSV);
        spv[T] = inv;
        tpv[T] = bp[g]*inv + betap[g] - mp[g]*inv;
    }

    // per-thread d-branch coefficients as channel pairs; fold center into bias
    f32x2 wx2[4], wy2[4], wz2[4], tq2[4];
    {
        float cx = px[n0 + p_t], cy = py[n0 + p_t], cz = pz[n0 + p_t];
        #pragma unroll
        for (int q = 0; q < 4; ++q) {
            float4 a = dcoef[c0 + 2*q];
            float4 c = dcoef[c0 + 2*q + 1];
            wx2[q][0] = a.x; wx2[q][1] = c.x;
            wy2[q][0] = a.y; wy2[q][1] = c.y;
            wz2[q][0] = a.z; wz2[q][1] = c.z;
            tq2[q][0] = a.w - (a.x*cx + a.y*cy + a.z*cz);
            tq2[q][1] = c.w - (c.x*cx + c.y*cy + c.z*cz);
        }
    }

    f32x2 facc2[2][2] = {{{0.f,0.f},{0.f,0.f}},{{0.f,0.f},{0.f,0.f}}};

    // prologue: stage planes 0,1 into buf0; issue 2,3
    stageRow(A3[0][0], p_t, c0, wx2, wy2, wz2, tq2, PA);
    PA = issueK(idx_row, 2, px, py, pz, Fb, c0);
    stageRow(A3[0][1], p_t, c0, wx2, wy2, wz2, tq2, PB);
    PB = issueK(idx_row, 3, px, py, pz, Fb, c0);
    __syncthreads();

    int cur = 0;
    #pragma unroll 1
    for (int i = 0; i < 7; ++i) {
        const int k = 2*i;
        // compute planes k, k+1 from buf[cur]
        mfmaPlane(A3[cur][0], r16, h, bfrag, spv, tpv, facc2);
        mfmaPlane(A3[cur][1], r16, h, bfrag, spv, tpv, facc2);
        // stage planes k+2, k+3 into buf[cur^1]; issue k+4, k+5
        stageRow(A3[cur^1][0], p_t, c0, wx2, wy2, wz2, tq2, PA);
        PA = issueK(idx_row, k+4, px, py, pz, Fb, c0);          // k+4 <= 16 always
        stageRow(A3[cur^1][1], p_t, c0, wx2, wy2, wz2, tq2, PB);
        if (k + 5 < KNN) PB = issueK(idx_row, k+5, px, py, pz, Fb, c0);
        __syncthreads();
        cur ^= 1;
    }
    // buf[cur] holds planes 14,15; PA holds plane 16
    mfmaPlane(A3[cur][0], r16, h, bfrag, spv, tpv, facc2);
    mfmaPlane(A3[cur][1], r16, h, bfrag, spv, tpv, facc2);
    stageRow(A3[cur^1][0], p_t, c0, wx2, wy2, wz2, tq2, PA);
    __syncthreads();
    mfmaPlane(A3[cur^1][0], r16, h, bfrag, spv, tpv, facc2);

    #pragma unroll
    for (int T = 0; T < 2; ++T) {
        int g = gb + T*16 + r16;
        f32x4 o;
        o[0] = facc2[T][0][0]; o[1] = facc2[T][0][1];
        o[2] = facc2[T][1][0]; o[3] = facc2[T][1][1];
        *(f32x4*)(out + ((size_t)b*CH + g)*NPT + n0 + 4*h) = o;
    }
}

extern "C" void kernel_launch(void* const* d_in, const int* in_sizes, int n_in,
                              void* d_out, int out_size, void* d_ws, size_t ws_size,
                              hipStream_t stream)
{
    const float* feats = (const float*)d_in[0];
    const float* pts   = (const float*)d_in[1];
    const int*   knn   = (const int*)d_in[2];
    const float* Wd    = (const float*)d_in[3];
    const float* bd    = (const float*)d_in[4];
    const float* gd    = (const float*)d_in[5];
    const float* betad = (const float*)d_in[6];
    const float* md    = (const float*)d_in[7];
    const float* vd    = (const float*)d_in[8];
    const float* Wf    = (const float*)d_in[9];
    const float* bfv   = (const float*)d_in[10];
    const float* gf    = (const float*)d_in[11];
    const float* betaf = (const float*)d_in[12];
    const float* mf    = (const float*)d_in[13];
    const float* vf    = (const float*)d_in[14];
    const float* Wp    = (const float*)d_in[15];
    const float* bp    = (const float*)d_in[16];
    const float* gp    = (const float*)d_in[17];
    const float* betap = (const float*)d_in[18];
    const float* mp    = (const float*)d_in[19];
    const float* vp    = (const float*)d_in[20];
    float* out = (float*)d_out;
    unsigned short* Fws = (unsigned short*)d_ws;   // B*N*128 bf16 = 10.24 MB

    k_feats<<<dim3(NB * NT32), 256, 0, stream>>>(feats, Wf, bfv, gf, betaf, mf, vf, Fws);
    k_main <<<dim3(NB * NT16), 256, 0, stream>>>(pts, knn, Fws, Wd, bd, gd, betad, md, vd,
                                                 Wp, bp, gp, betap, mp, vp, out);
}